// Round 4
// baseline (677.654 us; speedup 1.0000x reference)
//
#include <hip/hip_runtime.h>
#include <stdint.h>

#define B_    4
#define N_    2048
#define D_    4096
#define E_    64
#define TOKENS (B_ * N_)        // 8192
#define KT    32                // K-tile staged in LDS
#define TM    64                // tokens per block tile
#define KS    8                 // split-K factor (DO NOT CHANGE: logit bit-exactness)
#define KCHUNK (D_ / KS)        // 512
#define NITER (KCHUNK / KT)     // 16

typedef float vfloat4 __attribute__((ext_vector_type(4)));  // native vec for NT stores

// global -> LDS direct DMA, 16B per lane, wave-uniform LDS base + lane*16
#define GL2LDS16(g, s) __builtin_amdgcn_global_load_lds(                     \
    (const __attribute__((address_space(1))) void*)(g),                      \
    (__attribute__((address_space(3))) void*)(s), 16, 0, 0)

// ---------------------------------------------------------------------------
// K1: split-K fp32 GEMM fused with d_out zero-fill. ROUND-4 RESTRUCTURE.
// Evidence: three different K1s (R0/R1/R2) all ~110 us with VALU/LDS/HBM each
// ~30% -> stall-bound, not throughput-bound. The per-tile __syncthreads drains
// vmcnt(0) (NT stores + next-tile DMA) across all waves in lockstep.
// New shape: 1024 blocks x 1 wave (TM=64), thread tile 8 tok x 8 exp:
//   - no __syncthreads at all (single-wave block): per-wave s_waitcnt only,
//     4 independent blocks/CU cover each other's stalls.
//   - 8x8 fragments halve LDS bytes/FLOP vs 8x4 (128 b128 / 2048 FMA):
//     LDS floor 61 -> 41 us.
//   - stage(next) issued mid-compute (after kk4 0-3) so the top-of-tile
//     vmcnt(0) finds it ~1000+ cycles old.
//   - A swizzle: LDS[row][slot] holds k4 = slot ^ ((row>>3)&7); DMA source
//     pre-swizzled, read side applies same XOR -> conflict-free b128 reads
//     (8 groups of 8 broadcast lanes, distinct 16B columns).
// Accumulation order per (token,expert,kc) unchanged (ascending k, fp32 fmac)
// -> logits bit-identical. LDS 32 KB/block.
// Each block streams its 10240-float4 slice of d_out as zeros (NT),
// interleaved with the K-loop. Block 0 zeroes probsum + the two loss slots.
// ---------------------------------------------------------------------------
__global__ __launch_bounds__(64) void k_gemm_z(const float* __restrict__ A,
                                               const float* __restrict__ W,
                                               float* __restrict__ P,
                                               float* __restrict__ out,
                                               float* __restrict__ probsum,
                                               float* __restrict__ losses) {
    __shared__ float As[2][TM][KT];   // [tok][16B-slot swizzled], DMA-linear
    __shared__ float Ws[2][KT][E_];   // global-contiguous tile, DMA-linear

    const int l     = threadIdx.x;     // lane 0..63 (single wave)
    const int tok0  = blockIdx.x * TM;
    const int kc    = blockIdx.y;
    const int kbase = kc * KCHUNK;
    const int blin  = kc * gridDim.x + blockIdx.x;   // 0..1023

    const int t0 = (l >> 3) * 8;       // token offset 0..56
    const int e0 = (l & 7) * 8;        // expert offset 0..56
    const int sw = l >> 3;             // read swizzle key = (row>>3)&7

    // --- DMA source pointers (advance by KT each tile) ---------------------
    // A: issue i (0..7) covers tokens i*8..i*8+7; lane l -> tok i*8+(l>>3),
    //    LDS slot l&7; source k4 = (l&7)^i so LDS[row][slot] holds
    //    k4 = slot ^ ((row>>3)&7)  (row>>3 == i for this issue).
    const float* pA[8];
    #pragma unroll
    for (int i = 0; i < 8; ++i)
        pA[i] = A + (size_t)(tok0 + i * 8 + (l >> 3)) * D_ + kbase
                  + ((l & 7) ^ i) * 4;
    // W: tile is 8 KB contiguous; issue j (0..7) covers rows j*4..j*4+3.
    const float* pW[8];
    #pragma unroll
    for (int j = 0; j < 8; ++j)
        pW[j] = W + (size_t)(kbase + j * 4 + (l >> 4)) * E_ + (l & 15) * 4;

    // zero-fill: block covers float4 range [blin*10240, (blin+1)*10240)
    vfloat4* zbase = reinterpret_cast<vfloat4*>(out) + (size_t)blin * 10240 + l;
    const vfloat4 z4 = {0.f, 0.f, 0.f, 0.f};

    if (blin == 0) {
        #pragma unroll
        for (int q = 0; q < 4; ++q) probsum[l + q * 64] = 0.f;  // 256 entries
        if (l < 2) losses[l] = 0.f;
    }

    float acc[8][8];
    #pragma unroll
    for (int i = 0; i < 8; ++i)
        #pragma unroll
        for (int j = 0; j < 8; ++j) acc[i][j] = 0.f;

    auto STAGE = [&](int b) {
        #pragma unroll
        for (int q = 0; q < 8; ++q) { GL2LDS16(pA[q], &As[b][q * 8][0]); pA[q] += KT; }
        #pragma unroll
        for (int q = 0; q < 8; ++q) { GL2LDS16(pW[q], &Ws[b][q * 4][0]); pW[q] += KT * E_; }
    };
    auto ZST = [&](int t) {
        #pragma unroll
        for (int j = 0; j < 10; ++j)
            __builtin_nontemporal_store(z4, zbase + (size_t)(t * 10 + j) * 64);
    };
    auto COMPUTE = [&](int b, int lo, int hi) {
        #pragma unroll
        for (int kk4 = lo; kk4 < hi; ++kk4) {
            float4 av[8];
            const int so = ((kk4 ^ sw) << 2);   // swizzled 16B slot (floats)
            #pragma unroll
            for (int i = 0; i < 8; ++i)
                av[i] = *reinterpret_cast<const float4*>(&As[b][t0 + i][so]);
            #pragma unroll
            for (int k = 0; k < 4; ++k) {       // kk ascending within tile
                const float4 w0 = *reinterpret_cast<const float4*>(&Ws[b][kk4 * 4 + k][e0]);
                const float4 w1 = *reinterpret_cast<const float4*>(&Ws[b][kk4 * 4 + k][e0 + 4]);
                #pragma unroll
                for (int i = 0; i < 8; ++i) {
                    const float a = (k == 0) ? av[i].x : (k == 1) ? av[i].y
                                  : (k == 2) ? av[i].z : av[i].w;
                    acc[i][0] += a * w0.x; acc[i][1] += a * w0.y;
                    acc[i][2] += a * w0.z; acc[i][3] += a * w0.w;
                    acc[i][4] += a * w1.x; acc[i][5] += a * w1.y;
                    acc[i][6] += a * w1.z; acc[i][7] += a * w1.w;
                }
            }
        }
    };

    STAGE(0);                           // tile 0 -> buf 0

    #pragma unroll 1
    for (int kt = 0; kt < NITER; kt += 2) {
        // ---- tile kt (buf 0) ----
        asm volatile("s_waitcnt vmcnt(0)" ::: "memory");  // buf0 DMA complete
        COMPUTE(0, 0, 4);
        ZST(kt);
        if (kt + 1 < NITER) STAGE(1);   // tile kt+1 -> buf1, hides under kk4 4-7
        COMPUTE(0, 4, 8);
        // ---- tile kt+1 (buf 1) ----
        asm volatile("s_waitcnt vmcnt(0)" ::: "memory");  // buf1 DMA complete
        COMPUTE(1, 0, 4);
        ZST(kt + 1);
        if (kt + 2 < NITER) STAGE(0);   // tile kt+2 -> buf0
        COMPUTE(1, 4, 8);
    }

    float* base = P + ((size_t)kc * TOKENS + tok0) * E_;
    #pragma unroll
    for (int i = 0; i < 8; ++i) {
        *reinterpret_cast<float4*>(&base[(size_t)(t0 + i) * E_ + e0]) =
            make_float4(acc[i][0], acc[i][1], acc[i][2], acc[i][3]);
        *reinterpret_cast<float4*>(&base[(size_t)(t0 + i) * E_ + e0 + 4]) =
            make_float4(acc[i][4], acc[i][5], acc[i][6], acc[i][7]);
    }
}

// ---------------------------------------------------------------------------
// K2: reduce split-K partials; per-token softmax stats. UNCHANGED from R3
// (256 blocks x 32 tokens, register probsum partials, 16K atomics).
// ---------------------------------------------------------------------------
__global__ __launch_bounds__(256) void k_softmax(const float* __restrict__ P,
                                                 int* __restrict__ idx,
                                                 float* __restrict__ gate,
                                                 float* __restrict__ probsum,
                                                 float* __restrict__ out_z) {
    const int tid  = threadIdx.x;
    const int wid  = tid >> 6;
    const int lane = tid & 63;
    const int tok0 = blockIdx.x * 32 + wid * 8;   // 8 tokens per wave

    float ps = 0.f;   // per-lane (=expert) probsum partial over 8 tokens
    float zz = 0.f;   // per-wave z partial (accumulated on lane 0)

    #pragma unroll
    for (int t = 0; t < 8; ++t) {
        const int tok = tok0 + t;

        float l = 0.f;
        #pragma unroll
        for (int kc = 0; kc < KS; ++kc)
            l += P[((size_t)kc * TOKENS + tok) * E_ + lane];

        // wave argmax, first-index tie-break (matches numpy)
        float m = l; int mi = lane;
        #pragma unroll
        for (int off = 32; off > 0; off >>= 1) {
            const float om = __shfl_down(m, off);
            const int   oi = __shfl_down(mi, off);
            if (om > m || (om == m && oi < mi)) { m = om; mi = oi; }
        }
        m  = __shfl(m, 0);
        mi = __shfl(mi, 0);

        const float p = __expf(l - m);
        float s = p;
        #pragma unroll
        for (int off = 32; off > 0; off >>= 1) s += __shfl_down(s, off);
        s = __shfl(s, 0);

        ps += p / s;
        if (lane == 0) {
            const float lse = m + logf(s);
            zz += lse * lse;
            idx[tok]  = mi;
            gate[tok] = 1.0f / s;             // exp(m-m)/s = max prob
        }
    }

    __shared__ float pacc[4][E_];
    __shared__ float zv[4];
    pacc[wid][lane] = ps;
    if (lane == 0) zv[wid] = zz;
    __syncthreads();

    if (tid < E_) {
        const float v = pacc[0][tid] + pacc[1][tid] + pacc[2][tid] + pacc[3][tid];
        const int b = (blockIdx.x * 32) / N_;  // block never crosses batch
        atomicAdd(&probsum[b * E_ + tid], v);
    }
    if (tid == 0)
        atomicAdd(out_z, (zv[0] + zv[1] + zv[2] + zv[3]) * (1.0f / (float)TOKENS));
}

// ---------------------------------------------------------------------------
// K3: ordered position-in-expert via wave ballot (matches reference cumsum),
// scatter into dispatch/combine + aux-loss fused. One wave per (b,e).
// UNCHANGED.
// ---------------------------------------------------------------------------
__global__ __launch_bounds__(64) void k_posloss(const int* __restrict__ idx,
                                                const float* __restrict__ gate,
                                                const float* __restrict__ probsum,
                                                float* __restrict__ out,
                                                float* __restrict__ out_aux,
                                                int C, size_t half) {
    const int b = blockIdx.x >> 6;
    const int e = blockIdx.x & 63;
    const int lane = threadIdx.x;
    const int*   ib = idx  + b * N_;
    const float* gb = gate + b * N_;
    float* ob = out + (size_t)b * N_ * E_ * C;   // dispatch base for batch b

    int running = 0;
    for (int step = 0; step < N_ / 64; ++step) {
        const int t = step * 64 + lane;
        const bool match = (ib[t] == e);
        const unsigned long long mask = __ballot(match);
        if (match) {
            const int p = running + __popcll(mask & ((1ull << lane) - 1ull));
            if (p < C) {
                const size_t off = (size_t)t * E_ * C + (size_t)e * C + p;
                ob[off] = 1.0f;            // dispatch
                ob[half + off] = gb[t];    // combine
            }
        }
        running += __popcll(mask);
    }
    if (lane == 0)   // aux = sum(count * probsum) * E^2/(B*E*N*N) = sum/262144
        atomicAdd(out_aux,
                  (float)running * probsum[b * E_ + e] * (1.0f / 262144.0f));
}

// ---------------------------------------------------------------------------
extern "C" void kernel_launch(void* const* d_in, const int* in_sizes, int n_in,
                              void* d_out, int out_size, void* d_ws, size_t ws_size,
                              hipStream_t stream) {
    const float* A = (const float*)d_in[0];
    const float* W = (const float*)d_in[1];
    float* out = (float*)d_out;

    const size_t half = ((size_t)out_size - 2) / 2;          // TOKENS*E*C
    const int C = (int)(half / ((size_t)TOKENS * E_));       // 40

    float* P = (float*)d_ws;
    size_t off = (size_t)KS * TOKENS * E_;
    int*   idx     = (int*)(P + off);   off += TOKENS;
    float* gate    = P + off;           off += TOKENS;
    float* probsum = P + off;           off += B_ * E_;

    float* out_aux = out + 2 * half;
    float* out_z   = out + 2 * half + 1;

    // k_gemm_z zeroes all of d_out (2*half floats via per-block NT-store
    // slices; 2*half = 41,943,040 floats = 1024 blocks * 10240 float4
    // exactly) plus probsum and the two loss scalars (block 0).
    k_gemm_z<<<dim3(TOKENS / TM, KS), 64, 0, stream>>>(A, W, P, out, probsum,
                                                       out_aux);
    k_softmax<<<TOKENS / 32, 256, 0, stream>>>(P, idx, gate, probsum, out_z);
    k_posloss<<<B_ * E_, 64, 0, stream>>>(idx, gate, probsum, out, out_aux, C, half);
}

// Round 5
// 344.450 us; speedup vs baseline: 1.9673x; 1.9673x over previous
//
#include <hip/hip_runtime.h>
#include <stdint.h>

#define B_    4
#define N_    2048
#define D_    4096
#define E_    64
#define TOKENS (B_ * N_)        // 8192
#define KT    32                // K-tile staged in LDS
#define TM    128               // tokens per block tile
#define KS    8                 // split-K factor (DO NOT CHANGE: logit bit-exactness)
#define KCHUNK (D_ / KS)        // 512
#define NITER (KCHUNK / KT)     // 16

typedef float vfloat4 __attribute__((ext_vector_type(4)));  // native vec for NT stores

// global -> LDS direct DMA, 16B per lane, wave-uniform LDS base + lane*16
#define GL2LDS16(g, s) __builtin_amdgcn_global_load_lds(                     \
    (const __attribute__((address_space(1))) void*)(g),                      \
    (__attribute__((address_space(3))) void*)(s), 16, 0, 0)

// ---------------------------------------------------------------------------
// K1: split-K fp32 GEMM fused with d_out zero-fill.
// Body/addressing/accumulation = Round-2 kernel (proven 108 us, VGPR 96,
// conflicts 0, bit-exact logits). ROUND-5 CHANGE: sync only.
//   R2's per-tile __syncthreads = s_waitcnt vmcnt(0) lgkmcnt(0) + s_barrier:
//   it drains the 5 NT zero-stores to HBM (~600+ cyc each to retire) and the
//   6 prefetch DMAs every tile, all 4 waves in lockstep. R4's failed probe
//   aside, R0-R2 all pinned at ~110 us with every pipe at 30% -> stall-bound
//   on exactly this drain.
//   Now: per-wave counted wait `s_waitcnt vmcnt(5)` (retires exactly the 6
//   gload_lds issued this tile; the 5 NT stores issued AFTER them may remain
//   in flight) + raw s_barrier, once per tile, skipped after the last tile.
//   sched_barrier(0) between STAGE and ZST pins load-before-store issue
//   order so the vmcnt count is exact. One barrier/tile is sufficient: the
//   end-of-tile barrier separates all reads of buf `nxt` (done in tile t-1)
//   from tile t+1's DMA writes into it.
// ---------------------------------------------------------------------------
__global__ __launch_bounds__(256) void k_gemm_z(const float* __restrict__ A,
                                                const float* __restrict__ W,
                                                float* __restrict__ P,
                                                float* __restrict__ out,
                                                float* __restrict__ probsum,
                                                float* __restrict__ losses) {
    __shared__ float As[2][TM][KT];   // [tok][16B-slot swizzled], DMA-linear
    __shared__ float Ws[2][KT][E_];   // global-contiguous tile, DMA-linear

    const int tid   = threadIdx.x;
    const int l     = tid & 63;        // lane
    const int w     = tid >> 6;        // wave 0..3
    const int tok0  = blockIdx.x * TM;
    const int kc    = blockIdx.y;
    const int kbase = kc * KCHUNK;
    const int blin  = kc * gridDim.x + blockIdx.x;   // 0..511

    const int t0 = (tid >> 4) * 8;     // token offset 0..120
    const int e0 = (tid & 15) * 4;     // expert offset 0..60
    const int sw = (tid >> 4) & 7;     // read-side swizzle key = (tok>>3)&7

    // --- DMA source pointers (advance by KT each iter) ---------------------
    // A: issue i (= w*4+q, 0..15) covers tokens i*8..i*8+7; lane l ->
    //    tok i*8+(l>>3), slot l&7; source k4 = (l&7)^(i&7) so that
    //    LDS[tok][slot] holds k4 = slot ^ ((tok>>3)&7).
    const float* pA[4];
    #pragma unroll
    for (int q = 0; q < 4; ++q) {
        const int i  = w * 4 + q;
        const int tk = i * 8 + (l >> 3);
        const int ks = (l & 7) ^ (i & 7);
        pA[q] = A + (size_t)(tok0 + tk) * D_ + kbase + ks * 4;
    }
    // W: tile is 8 KB contiguous in global; issue j (= w*2+q, 0..7) covers
    //    rows j*4..j*4+3 (1 KB each), linear (2-way read aliasing is free).
    const float* pW[2];
    #pragma unroll
    for (int q = 0; q < 2; ++q) {
        const int j  = w * 2 + q;
        const int kk = j * 4 + (l >> 4);
        pW[q] = W + (size_t)(kbase + kk) * E_ + (l & 15) * 4;
    }

    // zero-fill: block covers float4 range [blin*20480, (blin+1)*20480)
    vfloat4* zbase = reinterpret_cast<vfloat4*>(out) + (size_t)blin * 20480 + tid;
    const vfloat4 z4 = {0.f, 0.f, 0.f, 0.f};

    if (blin == 0) {
        probsum[tid] = 0.f;            // 256 entries, 256 threads
        if (tid < 2) losses[tid] = 0.f;
    }

    // prologue: stage tile 0 into buf 0 (6 gload_lds per wave)
    #pragma unroll
    for (int q = 0; q < 4; ++q) {
        GL2LDS16(pA[q], &As[0][(w * 4 + q) * 8][0]);
        pA[q] += KT;
    }
    #pragma unroll
    for (int q = 0; q < 2; ++q) {
        GL2LDS16(pW[q], &Ws[0][(w * 2 + q) * 4][0]);
        pW[q] += KT * E_;
    }
    asm volatile("s_waitcnt vmcnt(0)" ::: "memory");  // drain prologue DMA
    __builtin_amdgcn_s_barrier();                      // buf0 ready for all

    float acc[8][4];
    #pragma unroll
    for (int i = 0; i < 8; ++i)
        #pragma unroll
        for (int j = 0; j < 4; ++j) acc[i][j] = 0.f;

    #pragma unroll 1
    for (int kt = 0; kt < NITER; ++kt) {
        const int cur = kt & 1;
        const int nxt = cur ^ 1;
        const bool more = (kt + 1 < NITER);

        // issue next-tile DMA first: whole compute phase hides the latency
        if (more) {
            #pragma unroll
            for (int q = 0; q < 4; ++q) {
                GL2LDS16(pA[q], &As[nxt][(w * 4 + q) * 8][0]);
                pA[q] += KT;
            }
            #pragma unroll
            for (int q = 0; q < 2; ++q) {
                GL2LDS16(pW[q], &Ws[nxt][(w * 2 + q) * 4][0]);
                pW[q] += KT * E_;
            }
        }
        // pin issue order: all 6 DMA loads precede the 5 NT stores, so
        // vmcnt(5) below retires exactly the loads.
        __builtin_amdgcn_sched_barrier(0);

        // interleaved zero stores: 5/iter * 16 iters = 80 = 20480/256
        #pragma unroll
        for (int j = 0; j < 5; ++j)
            __builtin_nontemporal_store(z4, zbase + (size_t)(kt * 5 + j) * 256);

        #pragma unroll
        for (int kk4 = 0; kk4 < 8; ++kk4) {
            float4 av[8];
            const int so = ((kk4 ^ sw) << 2);   // swizzled 16B slot
            #pragma unroll
            for (int i = 0; i < 8; ++i)
                av[i] = *reinterpret_cast<const float4*>(&As[cur][t0 + i][so]);
            #pragma unroll
            for (int k = 0; k < 4; ++k) {       // kk = kt*KT + kk4*4 + k, ascending
                const float4 w0 = *reinterpret_cast<const float4*>(&Ws[cur][kk4 * 4 + k][e0]);
                #pragma unroll
                for (int i = 0; i < 8; ++i) {
                    const float a = (k == 0) ? av[i].x : (k == 1) ? av[i].y
                                  : (k == 2) ? av[i].z : av[i].w;
                    acc[i][0] += a * w0.x; acc[i][1] += a * w0.y;
                    acc[i][2] += a * w0.z; acc[i][3] += a * w0.w;
                }
            }
        }

        if (more) {
            // counted wait: <=5 outstanding leaves only the NT stores; the 6
            // DMA loads for buf nxt are retired. Then one barrier: every
            // wave's DMA landed, and all reads of buf nxt (tile kt-1)
            // happened before this point.
            asm volatile("s_waitcnt vmcnt(5)" ::: "memory");
            __builtin_amdgcn_s_barrier();
        }
    }

    float* base = P + ((size_t)kc * TOKENS + tok0) * E_;
    #pragma unroll
    for (int i = 0; i < 8; ++i)
        *reinterpret_cast<float4*>(&base[(size_t)(t0 + i) * E_ + e0]) =
            make_float4(acc[i][0], acc[i][1], acc[i][2], acc[i][3]);
}

// ---------------------------------------------------------------------------
// K2: reduce split-K partials; per-token softmax stats. UNCHANGED from R3
// (256 blocks x 32 tokens, register probsum partials, 16K atomics).
// ---------------------------------------------------------------------------
__global__ __launch_bounds__(256) void k_softmax(const float* __restrict__ P,
                                                 int* __restrict__ idx,
                                                 float* __restrict__ gate,
                                                 float* __restrict__ probsum,
                                                 float* __restrict__ out_z) {
    const int tid  = threadIdx.x;
    const int wid  = tid >> 6;
    const int lane = tid & 63;
    const int tok0 = blockIdx.x * 32 + wid * 8;   // 8 tokens per wave

    float ps = 0.f;   // per-lane (=expert) probsum partial over 8 tokens
    float zz = 0.f;   // per-wave z partial (accumulated on lane 0)

    #pragma unroll
    for (int t = 0; t < 8; ++t) {
        const int tok = tok0 + t;

        float l = 0.f;
        #pragma unroll
        for (int kc = 0; kc < KS; ++kc)
            l += P[((size_t)kc * TOKENS + tok) * E_ + lane];

        // wave argmax, first-index tie-break (matches numpy)
        float m = l; int mi = lane;
        #pragma unroll
        for (int off = 32; off > 0; off >>= 1) {
            const float om = __shfl_down(m, off);
            const int   oi = __shfl_down(mi, off);
            if (om > m || (om == m && oi < mi)) { m = om; mi = oi; }
        }
        m  = __shfl(m, 0);
        mi = __shfl(mi, 0);

        const float p = __expf(l - m);
        float s = p;
        #pragma unroll
        for (int off = 32; off > 0; off >>= 1) s += __shfl_down(s, off);
        s = __shfl(s, 0);

        ps += p / s;
        if (lane == 0) {
            const float lse = m + logf(s);
            zz += lse * lse;
            idx[tok]  = mi;
            gate[tok] = 1.0f / s;             // exp(m-m)/s = max prob
        }
    }

    __shared__ float pacc[4][E_];
    __shared__ float zv[4];
    pacc[wid][lane] = ps;
    if (lane == 0) zv[wid] = zz;
    __syncthreads();

    if (tid < E_) {
        const float v = pacc[0][tid] + pacc[1][tid] + pacc[2][tid] + pacc[3][tid];
        const int b = (blockIdx.x * 32) / N_;  // block never crosses batch
        atomicAdd(&probsum[b * E_ + tid], v);
    }
    if (tid == 0)
        atomicAdd(out_z, (zv[0] + zv[1] + zv[2] + zv[3]) * (1.0f / (float)TOKENS));
}

// ---------------------------------------------------------------------------
// K3: ordered position-in-expert via wave ballot (matches reference cumsum),
// scatter into dispatch/combine + aux-loss fused. One wave per (b,e).
// UNCHANGED.
// ---------------------------------------------------------------------------
__global__ __launch_bounds__(64) void k_posloss(const int* __restrict__ idx,
                                                const float* __restrict__ gate,
                                                const float* __restrict__ probsum,
                                                float* __restrict__ out,
                                                float* __restrict__ out_aux,
                                                int C, size_t half) {
    const int b = blockIdx.x >> 6;
    const int e = blockIdx.x & 63;
    const int lane = threadIdx.x;
    const int*   ib = idx  + b * N_;
    const float* gb = gate + b * N_;
    float* ob = out + (size_t)b * N_ * E_ * C;   // dispatch base for batch b

    int running = 0;
    for (int step = 0; step < N_ / 64; ++step) {
        const int t = step * 64 + lane;
        const bool match = (ib[t] == e);
        const unsigned long long mask = __ballot(match);
        if (match) {
            const int p = running + __popcll(mask & ((1ull << lane) - 1ull));
            if (p < C) {
                const size_t off = (size_t)t * E_ * C + (size_t)e * C + p;
                ob[off] = 1.0f;            // dispatch
                ob[half + off] = gb[t];    // combine
            }
        }
        running += __popcll(mask);
    }
    if (lane == 0)   // aux = sum(count * probsum) * E^2/(B*E*N*N) = sum/262144
        atomicAdd(out_aux,
                  (float)running * probsum[b * E_ + e] * (1.0f / 262144.0f));
}

// ---------------------------------------------------------------------------
extern "C" void kernel_launch(void* const* d_in, const int* in_sizes, int n_in,
                              void* d_out, int out_size, void* d_ws, size_t ws_size,
                              hipStream_t stream) {
    const float* A = (const float*)d_in[0];
    const float* W = (const float*)d_in[1];
    float* out = (float*)d_out;

    const size_t half = ((size_t)out_size - 2) / 2;          // TOKENS*E*C
    const int C = (int)(half / ((size_t)TOKENS * E_));       // 40

    float* P = (float*)d_ws;
    size_t off = (size_t)KS * TOKENS * E_;
    int*   idx     = (int*)(P + off);   off += TOKENS;
    float* gate    = P + off;           off += TOKENS;
    float* probsum = P + off;           off += B_ * E_;

    float* out_aux = out + 2 * half;
    float* out_z   = out + 2 * half + 1;

    // k_gemm_z zeroes all of d_out (2*half floats via per-block NT-store
    // slices; 2*half = 41,943,040 floats = 512 blocks * 20480 float4 exactly)
    // plus probsum and the two loss scalars (block 0). No hipMemsetAsync.
    k_gemm_z<<<dim3(TOKENS / TM, KS), 256, 0, stream>>>(A, W, P, out, probsum,
                                                        out_aux);
    k_softmax<<<TOKENS / 32, 256, 0, stream>>>(P, idx, gate, probsum, out_z);
    k_posloss<<<B_ * E_, 64, 0, stream>>>(idx, gate, probsum, out, out_aux, C, half);
}

// Round 6
// 340.569 us; speedup vs baseline: 1.9898x; 1.0114x over previous
//
#include <hip/hip_runtime.h>
#include <stdint.h>

#define B_    4
#define N_    2048
#define D_    4096
#define E_    64
#define TOKENS (B_ * N_)        // 8192
#define KT    32                // K-tile staged in LDS
#define TM    128               // tokens per block tile
#define KS    8                 // split-K factor (DO NOT CHANGE: logit bit-exactness)
#define KCHUNK (D_ / KS)        // 512
#define NITER (KCHUNK / KT)     // 16

typedef float vfloat4 __attribute__((ext_vector_type(4)));  // native vec for NT stores

// global -> LDS direct DMA, 16B per lane, wave-uniform LDS base + lane*16
#define GL2LDS16(g, s) __builtin_amdgcn_global_load_lds(                     \
    (const __attribute__((address_space(1))) void*)(g),                      \
    (__attribute__((address_space(3))) void*)(s), 16, 0, 0)

// ---------------------------------------------------------------------------
// K1: split-K fp32 GEMM fused with d_out zero-fill.
// Body = Round-2 kernel (proven 108 us, VGPR 96, conflicts 0, bit-exact
// logits). ROUND-6 CHANGE: W operand comes straight from global/L2; the Ws
// LDS buffer and its DMA are deleted.
//   Why: per wave-tile the old loop issued 96 ds_read_b128 (64 A + 32 W) vs
//   1024 FMA wave-instrs; at 8-12cyc/b128 and 8 waves/CU the shared LDS unit
//   needs 41-61us of the 108 -> LDS-instruction-throughput is the tightest
//   pipe. W is 1 MB total (L2-resident on every XCD) and each wave touches
//   its 8 KB W-tile once per K-step with 4-lane broadcast -> ~64 KB/CU per
//   tile-round from L2, far under the per-CU L2 share. W addressing is one
//   pointer + literal offsets ((kk4*4+k)*256B, max 7936 < 8 KB imm) so the
//   compiler can hoist the 32 independent loads without any pinning.
//   __launch_bounds__(256,2) caps VGPR at 128 (R5 lesson: VGPR>128 halves
//   occupancy and costs more than any schedule win).
// Accumulation order per (token,expert,kc) unchanged (ascending k, fp32
// fmac, identical values) -> logits bit-identical.
// Each block streams its 20480-float4 slice of d_out as zeros (NT),
// interleaved with the K-loop. Block 0 zeroes probsum + the two loss slots.
// ---------------------------------------------------------------------------
__global__ __launch_bounds__(256, 2) void k_gemm_z(const float* __restrict__ A,
                                                   const float* __restrict__ W,
                                                   float* __restrict__ P,
                                                   float* __restrict__ out,
                                                   float* __restrict__ probsum,
                                                   float* __restrict__ losses) {
    __shared__ float As[2][TM][KT];   // [tok][16B-slot swizzled], DMA-linear

    const int tid   = threadIdx.x;
    const int l     = tid & 63;        // lane
    const int w     = tid >> 6;        // wave 0..3
    const int tok0  = blockIdx.x * TM;
    const int kc    = blockIdx.y;
    const int kbase = kc * KCHUNK;
    const int blin  = kc * gridDim.x + blockIdx.x;   // 0..511

    const int t0 = (tid >> 4) * 8;     // token offset 0..120
    const int e0 = (tid & 15) * 4;     // expert offset 0..60
    const int sw = (tid >> 4) & 7;     // read-side swizzle key = (tok>>3)&7

    // --- DMA source pointers for A (advance by KT each iter) ---------------
    // A: issue i (= w*4+q, 0..15) covers tokens i*8..i*8+7; lane l ->
    //    tok i*8+(l>>3), slot l&7; source k4 = (l&7)^(i&7) so that
    //    LDS[tok][slot] holds k4 = slot ^ ((tok>>3)&7).
    const float* pA[4];
    #pragma unroll
    for (int q = 0; q < 4; ++q) {
        const int i  = w * 4 + q;
        const int tk = i * 8 + (l >> 3);
        const int ks = (l & 7) ^ (i & 7);
        pA[q] = A + (size_t)(tok0 + tk) * D_ + kbase + ks * 4;
    }
    // W read pointer: row kbase+kk, experts e0..e0+3; offsets within a tile
    // are compile-time literals ((kk4*4+k)*E_ floats = 0..7936 bytes).
    const float* wp = W + (size_t)kbase * E_ + e0;

    // zero-fill: block covers float4 range [blin*20480, (blin+1)*20480)
    vfloat4* zbase = reinterpret_cast<vfloat4*>(out) + (size_t)blin * 20480 + tid;
    const vfloat4 z4 = {0.f, 0.f, 0.f, 0.f};

    if (blin == 0) {
        probsum[tid] = 0.f;            // 256 entries, 256 threads
        if (tid < 2) losses[tid] = 0.f;
    }

    // prologue: stage A tile 0 into buf 0 (4 gload_lds per wave)
    #pragma unroll
    for (int q = 0; q < 4; ++q) {
        GL2LDS16(pA[q], &As[0][(w * 4 + q) * 8][0]);
        pA[q] += KT;
    }
    __syncthreads();                   // buf0 ready

    float acc[8][4];
    #pragma unroll
    for (int i = 0; i < 8; ++i)
        #pragma unroll
        for (int j = 0; j < 4; ++j) acc[i][j] = 0.f;

    #pragma unroll 1
    for (int kt = 0; kt < NITER; ++kt) {
        const int cur = kt & 1;
        const int nxt = cur ^ 1;

        // issue next A-tile DMA first: whole compute phase hides the latency
        if (kt + 1 < NITER) {
            #pragma unroll
            for (int q = 0; q < 4; ++q) {
                GL2LDS16(pA[q], &As[nxt][(w * 4 + q) * 8][0]);
                pA[q] += KT;
            }
        }

        // interleaved zero stores: 5/iter * 16 iters = 80 = 20480/256
        #pragma unroll
        for (int j = 0; j < 5; ++j)
            __builtin_nontemporal_store(z4, zbase + (size_t)(kt * 5 + j) * 256);

        #pragma unroll
        for (int kk4 = 0; kk4 < 8; ++kk4) {
            float4 av[8];
            const int so = ((kk4 ^ sw) << 2);   // swizzled 16B slot
            #pragma unroll
            for (int i = 0; i < 8; ++i)
                av[i] = *reinterpret_cast<const float4*>(&As[cur][t0 + i][so]);
            #pragma unroll
            for (int k = 0; k < 4; ++k) {       // kk = kt*KT + kk4*4 + k, ascending
                const float4 w0 = *reinterpret_cast<const float4*>(
                    wp + (kk4 * 4 + k) * E_);   // L2-hot, literal offset
                #pragma unroll
                for (int i = 0; i < 8; ++i) {
                    const float a = (k == 0) ? av[i].x : (k == 1) ? av[i].y
                                  : (k == 2) ? av[i].z : av[i].w;
                    acc[i][0] += a * w0.x; acc[i][1] += a * w0.y;
                    acc[i][2] += a * w0.z; acc[i][3] += a * w0.w;
                }
            }
        }
        wp += KT * E_;                 // next W tile

        __syncthreads();               // drains this iter's DMA for next iter
    }

    float* base = P + ((size_t)kc * TOKENS + tok0) * E_;
    #pragma unroll
    for (int i = 0; i < 8; ++i)
        *reinterpret_cast<float4*>(&base[(size_t)(t0 + i) * E_ + e0]) =
            make_float4(acc[i][0], acc[i][1], acc[i][2], acc[i][3]);
}

// ---------------------------------------------------------------------------
// K2: reduce split-K partials; per-token softmax stats. UNCHANGED from R3
// (256 blocks x 32 tokens, register probsum partials, 16K atomics).
// ---------------------------------------------------------------------------
__global__ __launch_bounds__(256) void k_softmax(const float* __restrict__ P,
                                                 int* __restrict__ idx,
                                                 float* __restrict__ gate,
                                                 float* __restrict__ probsum,
                                                 float* __restrict__ out_z) {
    const int tid  = threadIdx.x;
    const int wid  = tid >> 6;
    const int lane = tid & 63;
    const int tok0 = blockIdx.x * 32 + wid * 8;   // 8 tokens per wave

    float ps = 0.f;   // per-lane (=expert) probsum partial over 8 tokens
    float zz = 0.f;   // per-wave z partial (accumulated on lane 0)

    #pragma unroll
    for (int t = 0; t < 8; ++t) {
        const int tok = tok0 + t;

        float l = 0.f;
        #pragma unroll
        for (int kc = 0; kc < KS; ++kc)
            l += P[((size_t)kc * TOKENS + tok) * E_ + lane];

        // wave argmax, first-index tie-break (matches numpy)
        float m = l; int mi = lane;
        #pragma unroll
        for (int off = 32; off > 0; off >>= 1) {
            const float om = __shfl_down(m, off);
            const int   oi = __shfl_down(mi, off);
            if (om > m || (om == m && oi < mi)) { m = om; mi = oi; }
        }
        m  = __shfl(m, 0);
        mi = __shfl(mi, 0);

        const float p = __expf(l - m);
        float s = p;
        #pragma unroll
        for (int off = 32; off > 0; off >>= 1) s += __shfl_down(s, off);
        s = __shfl(s, 0);

        ps += p / s;
        if (lane == 0) {
            const float lse = m + logf(s);
            zz += lse * lse;
            idx[tok]  = mi;
            gate[tok] = 1.0f / s;             // exp(m-m)/s = max prob
        }
    }

    __shared__ float pacc[4][E_];
    __shared__ float zv[4];
    pacc[wid][lane] = ps;
    if (lane == 0) zv[wid] = zz;
    __syncthreads();

    if (tid < E_) {
        const float v = pacc[0][tid] + pacc[1][tid] + pacc[2][tid] + pacc[3][tid];
        const int b = (blockIdx.x * 32) / N_;  // block never crosses batch
        atomicAdd(&probsum[b * E_ + tid], v);
    }
    if (tid == 0)
        atomicAdd(out_z, (zv[0] + zv[1] + zv[2] + zv[3]) * (1.0f / (float)TOKENS));
}

// ---------------------------------------------------------------------------
// K3: ordered position-in-expert via wave ballot (matches reference cumsum),
// scatter into dispatch/combine + aux-loss fused. One wave per (b,e).
// UNCHANGED.
// ---------------------------------------------------------------------------
__global__ __launch_bounds__(64) void k_posloss(const int* __restrict__ idx,
                                                const float* __restrict__ gate,
                                                const float* __restrict__ probsum,
                                                float* __restrict__ out,
                                                float* __restrict__ out_aux,
                                                int C, size_t half) {
    const int b = blockIdx.x >> 6;
    const int e = blockIdx.x & 63;
    const int lane = threadIdx.x;
    const int*   ib = idx  + b * N_;
    const float* gb = gate + b * N_;
    float* ob = out + (size_t)b * N_ * E_ * C;   // dispatch base for batch b

    int running = 0;
    for (int step = 0; step < N_ / 64; ++step) {
        const int t = step * 64 + lane;
        const bool match = (ib[t] == e);
        const unsigned long long mask = __ballot(match);
        if (match) {
            const int p = running + __popcll(mask & ((1ull << lane) - 1ull));
            if (p < C) {
                const size_t off = (size_t)t * E_ * C + (size_t)e * C + p;
                ob[off] = 1.0f;            // dispatch
                ob[half + off] = gb[t];    // combine
            }
        }
        running += __popcll(mask);
    }
    if (lane == 0)   // aux = sum(count * probsum) * E^2/(B*E*N*N) = sum/262144
        atomicAdd(out_aux,
                  (float)running * probsum[b * E_ + e] * (1.0f / 262144.0f));
}

// ---------------------------------------------------------------------------
extern "C" void kernel_launch(void* const* d_in, const int* in_sizes, int n_in,
                              void* d_out, int out_size, void* d_ws, size_t ws_size,
                              hipStream_t stream) {
    const float* A = (const float*)d_in[0];
    const float* W = (const float*)d_in[1];
    float* out = (float*)d_out;

    const size_t half = ((size_t)out_size - 2) / 2;          // TOKENS*E*C
    const int C = (int)(half / ((size_t)TOKENS * E_));       // 40

    float* P = (float*)d_ws;
    size_t off = (size_t)KS * TOKENS * E_;
    int*   idx     = (int*)(P + off);   off += TOKENS;
    float* gate    = P + off;           off += TOKENS;
    float* probsum = P + off;           off += B_ * E_;

    float* out_aux = out + 2 * half;
    float* out_z   = out + 2 * half + 1;

    // k_gemm_z zeroes all of d_out (2*half floats via per-block NT-store
    // slices; 2*half = 41,943,040 floats = 512 blocks * 20480 float4 exactly)
    // plus probsum and the two loss scalars (block 0). No hipMemsetAsync.
    k_gemm_z<<<dim3(TOKENS / TM, KS), 256, 0, stream>>>(A, W, P, out, probsum,
                                                        out_aux);
    k_softmax<<<TOKENS / 32, 256, 0, stream>>>(P, idx, gate, probsum, out_z);
    k_posloss<<<B_ * E_, 64, 0, stream>>>(idx, gate, probsum, out, out_aux, C, half);
}

// Round 7
// 308.430 us; speedup vs baseline: 2.1971x; 1.1042x over previous
//
#include <hip/hip_runtime.h>
#include <stdint.h>

#define B_    4
#define N_    2048
#define D_    4096
#define E_    64
#define TOKENS (B_ * N_)        // 8192
#define KT    32                // K-tile staged in LDS
#define TM    128               // tokens per block tile
#define KS    8                 // split-K factor (DO NOT CHANGE: logit bit-exactness)
#define KCHUNK (D_ / KS)        // 512
#define NITER (KCHUNK / KT)     // 16

typedef float vfloat4 __attribute__((ext_vector_type(4)));  // native vec for NT stores

// global -> LDS direct DMA, 16B per lane, wave-uniform LDS base + lane*16
#define GL2LDS16(g, s) __builtin_amdgcn_global_load_lds(                     \
    (const __attribute__((address_space(1))) void*)(g),                      \
    (__attribute__((address_space(3))) void*)(s), 16, 0, 0)

// ---------------------------------------------------------------------------
// K1: split-K fp32 GEMM (R2 body, proven 108 us / VGPR 96 / conflicts 0 /
// bit-exact) WITHOUT the d_out zero-fill. ROUND-7 CHANGE: un-mix the memory
// streams.
//   Evidence: six structurally different K1s (R0-R6: staging style, wave
//   count, sync style, W placement all varied) land 106-138 us; the only
//   invariant is the traffic -- 70 MB fetch + 180 MB NT-write at an
//   effective ~2.4 TB/s. The NT zero-store stream interleaved at
//   instruction granularity with the A-read stream forces read/write
//   turnaround in the memory system; the 6.3 TB/s ceiling is for clean
//   streams. So: zero-fill moves to K2 (pure write stream there), K1
//   becomes pure-read + small P write. Per-tile __syncthreads now drains
//   only the 4 prefetch DMAs (issued a full compute phase earlier);
//   LDS 48 KB -> 3 blocks/CU.
// Accumulation per (token,expert,kc) unchanged (ascending k, fp32 fmac) ->
// logits bit-identical. Block 0 zeroes probsum + the two loss slots (must
// precede K2's atomics; K1/K2 kernel boundary guarantees it).
// ---------------------------------------------------------------------------
__global__ __launch_bounds__(256) void k_gemm(const float* __restrict__ A,
                                              const float* __restrict__ W,
                                              float* __restrict__ P,
                                              float* __restrict__ probsum,
                                              float* __restrict__ losses) {
    __shared__ float As[2][TM][KT];   // [tok][16B-slot swizzled], DMA-linear
    __shared__ float Ws[2][KT][E_];   // global-contiguous tile, DMA-linear

    const int tid   = threadIdx.x;
    const int l     = tid & 63;        // lane
    const int w     = tid >> 6;        // wave 0..3
    const int tok0  = blockIdx.x * TM;
    const int kc    = blockIdx.y;
    const int kbase = kc * KCHUNK;
    const int blin  = kc * gridDim.x + blockIdx.x;   // 0..511

    const int t0 = (tid >> 4) * 8;     // token offset 0..120
    const int e0 = (tid & 15) * 4;     // expert offset 0..60
    const int sw = (tid >> 4) & 7;     // read-side swizzle key = (tok>>3)&7

    // --- DMA source pointers (advance by KT each iter) ---------------------
    // A: issue i (= w*4+q, 0..15) covers tokens i*8..i*8+7; lane l ->
    //    tok i*8+(l>>3), slot l&7; source k4 = (l&7)^(i&7) so that
    //    LDS[tok][slot] holds k4 = slot ^ ((tok>>3)&7).
    const float* pA[4];
    #pragma unroll
    for (int q = 0; q < 4; ++q) {
        const int i  = w * 4 + q;
        const int tk = i * 8 + (l >> 3);
        const int ks = (l & 7) ^ (i & 7);
        pA[q] = A + (size_t)(tok0 + tk) * D_ + kbase + ks * 4;
    }
    // W: tile is 8 KB contiguous in global; issue j (= w*2+q, 0..7) covers
    //    rows j*4..j*4+3 (1 KB each), linear (2-way read aliasing is free).
    const float* pW[2];
    #pragma unroll
    for (int q = 0; q < 2; ++q) {
        const int j  = w * 2 + q;
        const int kk = j * 4 + (l >> 4);
        pW[q] = W + (size_t)(kbase + kk) * E_ + (l & 15) * 4;
    }

    if (blin == 0) {
        probsum[tid] = 0.f;            // 256 entries, 256 threads
        if (tid < 2) losses[tid] = 0.f;
    }

    // prologue: stage tile 0 into buf 0 (6 gload_lds per wave)
    #pragma unroll
    for (int q = 0; q < 4; ++q) {
        GL2LDS16(pA[q], &As[0][(w * 4 + q) * 8][0]);
        pA[q] += KT;
    }
    #pragma unroll
    for (int q = 0; q < 2; ++q) {
        GL2LDS16(pW[q], &Ws[0][(w * 2 + q) * 4][0]);
        pW[q] += KT * E_;
    }
    __syncthreads();                   // buf0 ready

    float acc[8][4];
    #pragma unroll
    for (int i = 0; i < 8; ++i)
        #pragma unroll
        for (int j = 0; j < 4; ++j) acc[i][j] = 0.f;

    #pragma unroll 1
    for (int kt = 0; kt < NITER; ++kt) {
        const int cur = kt & 1;
        const int nxt = cur ^ 1;

        // issue next-tile DMA first: whole compute phase hides the latency
        if (kt + 1 < NITER) {
            #pragma unroll
            for (int q = 0; q < 4; ++q) {
                GL2LDS16(pA[q], &As[nxt][(w * 4 + q) * 8][0]);
                pA[q] += KT;
            }
            #pragma unroll
            for (int q = 0; q < 2; ++q) {
                GL2LDS16(pW[q], &Ws[nxt][(w * 2 + q) * 4][0]);
                pW[q] += KT * E_;
            }
        }

        #pragma unroll
        for (int kk4 = 0; kk4 < 8; ++kk4) {
            float4 av[8];
            const int so = ((kk4 ^ sw) << 2);   // swizzled 16B slot
            #pragma unroll
            for (int i = 0; i < 8; ++i)
                av[i] = *reinterpret_cast<const float4*>(&As[cur][t0 + i][so]);
            #pragma unroll
            for (int k = 0; k < 4; ++k) {       // kk = kt*KT + kk4*4 + k, ascending
                const float4 w0 = *reinterpret_cast<const float4*>(&Ws[cur][kk4 * 4 + k][e0]);
                #pragma unroll
                for (int i = 0; i < 8; ++i) {
                    const float a = (k == 0) ? av[i].x : (k == 1) ? av[i].y
                                  : (k == 2) ? av[i].z : av[i].w;
                    acc[i][0] += a * w0.x; acc[i][1] += a * w0.y;
                    acc[i][2] += a * w0.z; acc[i][3] += a * w0.w;
                }
            }
        }

        __syncthreads();               // drains this iter's DMA for next iter
    }

    float* base = P + ((size_t)kc * TOKENS + tok0) * E_;
    #pragma unroll
    for (int i = 0; i < 8; ++i)
        *reinterpret_cast<float4*>(&base[(size_t)(t0 + i) * E_ + e0]) =
            make_float4(acc[i][0], acc[i][1], acc[i][2], acc[i][3]);
}

// ---------------------------------------------------------------------------
// K2: split-K reduce + per-token softmax stats (R3 body: 256 blocks x 32
// tokens, register probsum partials, 16K atomics) PLUS the d_out zero-fill.
// ROUND-7: each block NT-streams its contiguous (4*C float4 per thread)
// slice of d_out as a pure write stream, interleaved with the token loop.
// K2->K3 kernel boundary guarantees zeros complete before K3's scatter.
// idx/gate/probsum/out_z math untouched (bit-exact).
// ---------------------------------------------------------------------------
__global__ __launch_bounds__(256) void k_softmax_z(const float* __restrict__ P,
                                                   int* __restrict__ idx,
                                                   float* __restrict__ gate,
                                                   float* __restrict__ probsum,
                                                   float* __restrict__ out_z,
                                                   float* __restrict__ out,
                                                   int C) {
    const int tid  = threadIdx.x;
    const int wid  = tid >> 6;
    const int lane = tid & 63;
    const int tok0 = blockIdx.x * 32 + wid * 8;   // 8 tokens per wave

    // zero-fill slab: 2*half floats = 262144*C float4 over 256 blocks
    // -> 1024*C float4 per block, 4*C per thread (C=40 -> 160).
    const int nz = 4 * C;
    vfloat4* zbase = reinterpret_cast<vfloat4*>(out)
                   + (size_t)blockIdx.x * 1024 * C + tid;
    const vfloat4 z4 = {0.f, 0.f, 0.f, 0.f};

    float ps = 0.f;   // per-lane (=expert) probsum partial over 8 tokens
    float zz = 0.f;   // per-wave z partial (accumulated on lane 0)

    #pragma unroll
    for (int t = 0; t < 8; ++t) {
        // interleaved zero stores: stride-8 over j covers [0, 4C) exactly
        for (int j = t; j < nz; j += 8)
            __builtin_nontemporal_store(z4, zbase + (size_t)j * 256);

        const int tok = tok0 + t;

        float l = 0.f;
        #pragma unroll
        for (int kc = 0; kc < KS; ++kc)
            l += P[((size_t)kc * TOKENS + tok) * E_ + lane];

        // wave argmax, first-index tie-break (matches numpy)
        float m = l; int mi = lane;
        #pragma unroll
        for (int off = 32; off > 0; off >>= 1) {
            const float om = __shfl_down(m, off);
            const int   oi = __shfl_down(mi, off);
            if (om > m || (om == m && oi < mi)) { m = om; mi = oi; }
        }
        m  = __shfl(m, 0);
        mi = __shfl(mi, 0);

        const float p = __expf(l - m);
        float s = p;
        #pragma unroll
        for (int off = 32; off > 0; off >>= 1) s += __shfl_down(s, off);
        s = __shfl(s, 0);

        ps += p / s;
        if (lane == 0) {
            const float lse = m + logf(s);
            zz += lse * lse;
            idx[tok]  = mi;
            gate[tok] = 1.0f / s;             // exp(m-m)/s = max prob
        }
    }

    __shared__ float pacc[4][E_];
    __shared__ float zv[4];
    pacc[wid][lane] = ps;
    if (lane == 0) zv[wid] = zz;
    __syncthreads();

    if (tid < E_) {
        const float v = pacc[0][tid] + pacc[1][tid] + pacc[2][tid] + pacc[3][tid];
        const int b = (blockIdx.x * 32) / N_;  // block never crosses batch
        atomicAdd(&probsum[b * E_ + tid], v);
    }
    if (tid == 0)
        atomicAdd(out_z, (zv[0] + zv[1] + zv[2] + zv[3]) * (1.0f / (float)TOKENS));
}

// ---------------------------------------------------------------------------
// K3: ordered position-in-expert via wave ballot (matches reference cumsum),
// scatter into dispatch/combine + aux-loss fused. One wave per (b,e).
// UNCHANGED.
// ---------------------------------------------------------------------------
__global__ __launch_bounds__(64) void k_posloss(const int* __restrict__ idx,
                                                const float* __restrict__ gate,
                                                const float* __restrict__ probsum,
                                                float* __restrict__ out,
                                                float* __restrict__ out_aux,
                                                int C, size_t half) {
    const int b = blockIdx.x >> 6;
    const int e = blockIdx.x & 63;
    const int lane = threadIdx.x;
    const int*   ib = idx  + b * N_;
    const float* gb = gate + b * N_;
    float* ob = out + (size_t)b * N_ * E_ * C;   // dispatch base for batch b

    int running = 0;
    for (int step = 0; step < N_ / 64; ++step) {
        const int t = step * 64 + lane;
        const bool match = (ib[t] == e);
        const unsigned long long mask = __ballot(match);
        if (match) {
            const int p = running + __popcll(mask & ((1ull << lane) - 1ull));
            if (p < C) {
                const size_t off = (size_t)t * E_ * C + (size_t)e * C + p;
                ob[off] = 1.0f;            // dispatch
                ob[half + off] = gb[t];    // combine
            }
        }
        running += __popcll(mask);
    }
    if (lane == 0)   // aux = sum(count * probsum) * E^2/(B*E*N*N) = sum/262144
        atomicAdd(out_aux,
                  (float)running * probsum[b * E_ + e] * (1.0f / 262144.0f));
}

// ---------------------------------------------------------------------------
extern "C" void kernel_launch(void* const* d_in, const int* in_sizes, int n_in,
                              void* d_out, int out_size, void* d_ws, size_t ws_size,
                              hipStream_t stream) {
    const float* A = (const float*)d_in[0];
    const float* W = (const float*)d_in[1];
    float* out = (float*)d_out;

    const size_t half = ((size_t)out_size - 2) / 2;          // TOKENS*E*C
    const int C = (int)(half / ((size_t)TOKENS * E_));       // 40

    float* P = (float*)d_ws;
    size_t off = (size_t)KS * TOKENS * E_;
    int*   idx     = (int*)(P + off);   off += TOKENS;
    float* gate    = P + off;           off += TOKENS;
    float* probsum = P + off;           off += B_ * E_;

    float* out_aux = out + 2 * half;
    float* out_z   = out + 2 * half + 1;

    // Stream separation: K1 = pure-read GEMM (A 128 MB + P 17 MB write);
    // K2 = softmax stats + pure NT-write zero-fill of d_out[0, 2*half)
    // (2*half = 262144*C float4 = 256 blocks * 1024*C exactly); K1 block 0
    // zeroes probsum + the two loss scalars before K2's atomics.
    k_gemm<<<dim3(TOKENS / TM, KS), 256, 0, stream>>>(A, W, P, probsum, out_aux);
    k_softmax_z<<<TOKENS / 32, 256, 0, stream>>>(P, idx, gate, probsum, out_z,
                                                 out, C);
    k_posloss<<<B_ * E_, 64, 0, stream>>>(idx, gate, probsum, out, out_aux, C, half);
}

// Round 8
// 306.949 us; speedup vs baseline: 2.2077x; 1.0048x over previous
//
#include <hip/hip_runtime.h>
#include <stdint.h>

#define B_    4
#define N_    2048
#define D_    4096
#define E_    64
#define TOKENS (B_ * N_)        // 8192
#define KT    32                // K-tile staged in LDS
#define TM    64                // tokens per block tile (R8: was 128)
#define KS    8                 // split-K factor (DO NOT CHANGE: logit bit-exactness)
#define KCHUNK (D_ / KS)        // 512
#define NITER (KCHUNK / KT)     // 16

typedef float vfloat4 __attribute__((ext_vector_type(4)));  // native vec for NT stores

// global -> LDS direct DMA, 16B per lane, wave-uniform LDS base + lane*16
#define GL2LDS16(g, s) __builtin_amdgcn_global_load_lds(                     \
    (const __attribute__((address_space(1))) void*)(g),                      \
    (__attribute__((address_space(3))) void*)(s), 16, 0, 0)

// ---------------------------------------------------------------------------
// K1: split-K fp32 GEMM, pure-read (zero-fill lives in K2 since R7).
// ROUND-8 CHANGE: grid-limited occupancy fix.
//   R7 evidence: OccupancyPercent 17.7% = ~5.7 waves/CU -- the 512-block
//   grid gives only 2 blocks/CU; LDS was never the limiter. K1 (~72 us) sits
//   far above its FMA/HBM/LDS floors (27/23/~25 us) -> latency-stall-bound
//   at 2 waves/SIMD.
//   Now: TM=64, 256 threads, 4tok x 4exp fragments -> 1024 blocks =
//   4 blocks/CU co-resident (LDS 32 KB), 16 waves/CU. Same DMA staging
//   (zero ds_write), same XOR swizzle re-derived for 4-row fragments
//   (reads resolve to 2 unique broadcast addresses on distinct banks ->
//   conflict-free), same double-buffer + prefetch-at-top schedule.
// Accumulation per (token,expert,kc): ascending k within chunk, one fp32
// fmac chain, identical order to R2/R7 -> logits bit-identical.
// Block 0 zeroes probsum + the two loss slots (before K2's atomics).
// ---------------------------------------------------------------------------
__global__ __launch_bounds__(256, 4) void k_gemm(const float* __restrict__ A,
                                                 const float* __restrict__ W,
                                                 float* __restrict__ P,
                                                 float* __restrict__ probsum,
                                                 float* __restrict__ losses) {
    __shared__ float As[2][TM][KT];   // 16 KB: [tok][16B-slot swizzled]
    __shared__ float Ws[2][KT][E_];   // 16 KB: global-contiguous tile

    const int tid   = threadIdx.x;
    const int l     = tid & 63;        // lane
    const int w     = tid >> 6;        // wave 0..3
    const int tok0  = blockIdx.x * TM;
    const int kc    = blockIdx.y;
    const int kbase = kc * KCHUNK;
    const int blin  = kc * gridDim.x + blockIdx.x;   // 0..1023

    const int t0 = (tid >> 4) * 4;     // token offset 0..60 (4 rows/thread)
    const int e0 = (tid & 15) * 4;     // expert offset 0..60
    const int sw = (tid >> 5) & 7;     // read swizzle key = (t0>>3), rows 4-aligned
                                       // never cross an 8-row group

    // --- DMA source pointers (advance by KT each tile) ---------------------
    // A: 8 issues of 1 KB per tile; wave w does issues i = {2w, 2w+1}.
    //    Issue i: lane l -> row i*8+(l>>3), LDS slot l&7; source k4-group
    //    ks = (l&7)^i so LDS[row][slot] holds k4 = slot ^ ((row>>3)&7).
    const float* pA[2];
    #pragma unroll
    for (int q = 0; q < 2; ++q) {
        const int i = w * 2 + q;
        pA[q] = A + (size_t)(tok0 + i * 8 + (l >> 3)) * D_ + kbase
                  + ((l & 7) ^ i) * 4;
    }
    // W: 8 issues of 1 KB (4 rows each); wave w does j = {2w, 2w+1}.
    const float* pW[2];
    #pragma unroll
    for (int q = 0; q < 2; ++q) {
        const int j = w * 2 + q;
        pW[q] = W + (size_t)(kbase + j * 4 + (l >> 4)) * E_ + (l & 15) * 4;
    }

    if (blin == 0) {
        probsum[tid] = 0.f;            // 256 entries, 256 threads
        if (tid < 2) losses[tid] = 0.f;
    }

    // prologue: stage tile 0 into buf 0 (4 gload_lds per wave)
    #pragma unroll
    for (int q = 0; q < 2; ++q) {
        GL2LDS16(pA[q], &As[0][(w * 2 + q) * 8][0]);
        pA[q] += KT;
    }
    #pragma unroll
    for (int q = 0; q < 2; ++q) {
        GL2LDS16(pW[q], &Ws[0][(w * 2 + q) * 4][0]);
        pW[q] += KT * E_;
    }
    __syncthreads();                   // buf0 ready

    float acc[4][4];
    #pragma unroll
    for (int i = 0; i < 4; ++i)
        #pragma unroll
        for (int j = 0; j < 4; ++j) acc[i][j] = 0.f;

    #pragma unroll 1
    for (int kt = 0; kt < NITER; ++kt) {
        const int cur = kt & 1;
        const int nxt = cur ^ 1;

        // issue next-tile DMA first: whole compute phase hides the latency
        if (kt + 1 < NITER) {
            #pragma unroll
            for (int q = 0; q < 2; ++q) {
                GL2LDS16(pA[q], &As[nxt][(w * 2 + q) * 8][0]);
                pA[q] += KT;
            }
            #pragma unroll
            for (int q = 0; q < 2; ++q) {
                GL2LDS16(pW[q], &Ws[nxt][(w * 2 + q) * 4][0]);
                pW[q] += KT * E_;
            }
        }

        #pragma unroll
        for (int kk4 = 0; kk4 < 8; ++kk4) {
            float4 av[4];
            const int so = ((kk4 ^ sw) << 2);   // swizzled 16B slot
            #pragma unroll
            for (int i = 0; i < 4; ++i)
                av[i] = *reinterpret_cast<const float4*>(&As[cur][t0 + i][so]);
            #pragma unroll
            for (int k = 0; k < 4; ++k) {       // kk = kt*KT + kk4*4 + k, ascending
                const float4 w0 = *reinterpret_cast<const float4*>(&Ws[cur][kk4 * 4 + k][e0]);
                #pragma unroll
                for (int i = 0; i < 4; ++i) {
                    const float a = (k == 0) ? av[i].x : (k == 1) ? av[i].y
                                  : (k == 2) ? av[i].z : av[i].w;
                    acc[i][0] += a * w0.x; acc[i][1] += a * w0.y;
                    acc[i][2] += a * w0.z; acc[i][3] += a * w0.w;
                }
            }
        }

        __syncthreads();               // drains this iter's DMA for next iter
    }

    float* base = P + ((size_t)kc * TOKENS + tok0) * E_;
    #pragma unroll
    for (int i = 0; i < 4; ++i)
        *reinterpret_cast<float4*>(&base[(size_t)(t0 + i) * E_ + e0]) =
            make_float4(acc[i][0], acc[i][1], acc[i][2], acc[i][3]);
}

// ---------------------------------------------------------------------------
// K2: split-K reduce + per-token softmax stats (R3 body) + d_out zero-fill
// (R7: pure NT-write stream). UNCHANGED from R7.
// ---------------------------------------------------------------------------
__global__ __launch_bounds__(256) void k_softmax_z(const float* __restrict__ P,
                                                   int* __restrict__ idx,
                                                   float* __restrict__ gate,
                                                   float* __restrict__ probsum,
                                                   float* __restrict__ out_z,
                                                   float* __restrict__ out,
                                                   int C) {
    const int tid  = threadIdx.x;
    const int wid  = tid >> 6;
    const int lane = tid & 63;
    const int tok0 = blockIdx.x * 32 + wid * 8;   // 8 tokens per wave

    // zero-fill slab: 2*half floats = 262144*C float4 over 256 blocks
    // -> 1024*C float4 per block, 4*C per thread (C=40 -> 160).
    const int nz = 4 * C;
    vfloat4* zbase = reinterpret_cast<vfloat4*>(out)
                   + (size_t)blockIdx.x * 1024 * C + tid;
    const vfloat4 z4 = {0.f, 0.f, 0.f, 0.f};

    float ps = 0.f;   // per-lane (=expert) probsum partial over 8 tokens
    float zz = 0.f;   // per-wave z partial (accumulated on lane 0)

    #pragma unroll
    for (int t = 0; t < 8; ++t) {
        // interleaved zero stores: stride-8 over j covers [0, 4C) exactly
        for (int j = t; j < nz; j += 8)
            __builtin_nontemporal_store(z4, zbase + (size_t)j * 256);

        const int tok = tok0 + t;

        float l = 0.f;
        #pragma unroll
        for (int kc = 0; kc < KS; ++kc)
            l += P[((size_t)kc * TOKENS + tok) * E_ + lane];

        // wave argmax, first-index tie-break (matches numpy)
        float m = l; int mi = lane;
        #pragma unroll
        for (int off = 32; off > 0; off >>= 1) {
            const float om = __shfl_down(m, off);
            const int   oi = __shfl_down(mi, off);
            if (om > m || (om == m && oi < mi)) { m = om; mi = oi; }
        }
        m  = __shfl(m, 0);
        mi = __shfl(mi, 0);

        const float p = __expf(l - m);
        float s = p;
        #pragma unroll
        for (int off = 32; off > 0; off >>= 1) s += __shfl_down(s, off);
        s = __shfl(s, 0);

        ps += p / s;
        if (lane == 0) {
            const float lse = m + logf(s);
            zz += lse * lse;
            idx[tok]  = mi;
            gate[tok] = 1.0f / s;             // exp(m-m)/s = max prob
        }
    }

    __shared__ float pacc[4][E_];
    __shared__ float zv[4];
    pacc[wid][lane] = ps;
    if (lane == 0) zv[wid] = zz;
    __syncthreads();

    if (tid < E_) {
        const float v = pacc[0][tid] + pacc[1][tid] + pacc[2][tid] + pacc[3][tid];
        const int b = (blockIdx.x * 32) / N_;  // block never crosses batch
        atomicAdd(&probsum[b * E_ + tid], v);
    }
    if (tid == 0)
        atomicAdd(out_z, (zv[0] + zv[1] + zv[2] + zv[3]) * (1.0f / (float)TOKENS));
}

// ---------------------------------------------------------------------------
// K3: ordered position-in-expert via wave ballot (matches reference cumsum),
// scatter into dispatch/combine + aux-loss fused. One wave per (b,e).
// UNCHANGED.
// ---------------------------------------------------------------------------
__global__ __launch_bounds__(64) void k_posloss(const int* __restrict__ idx,
                                                const float* __restrict__ gate,
                                                const float* __restrict__ probsum,
                                                float* __restrict__ out,
                                                float* __restrict__ out_aux,
                                                int C, size_t half) {
    const int b = blockIdx.x >> 6;
    const int e = blockIdx.x & 63;
    const int lane = threadIdx.x;
    const int*   ib = idx  + b * N_;
    const float* gb = gate + b * N_;
    float* ob = out + (size_t)b * N_ * E_ * C;   // dispatch base for batch b

    int running = 0;
    for (int step = 0; step < N_ / 64; ++step) {
        const int t = step * 64 + lane;
        const bool match = (ib[t] == e);
        const unsigned long long mask = __ballot(match);
        if (match) {
            const int p = running + __popcll(mask & ((1ull << lane) - 1ull));
            if (p < C) {
                const size_t off = (size_t)t * E_ * C + (size_t)e * C + p;
                ob[off] = 1.0f;            // dispatch
                ob[half + off] = gb[t];    // combine
            }
        }
        running += __popcll(mask);
    }
    if (lane == 0)   // aux = sum(count * probsum) * E^2/(B*E*N*N) = sum/262144
        atomicAdd(out_aux,
                  (float)running * probsum[b * E_ + e] * (1.0f / 262144.0f));
}

// ---------------------------------------------------------------------------
extern "C" void kernel_launch(void* const* d_in, const int* in_sizes, int n_in,
                              void* d_out, int out_size, void* d_ws, size_t ws_size,
                              hipStream_t stream) {
    const float* A = (const float*)d_in[0];
    const float* W = (const float*)d_in[1];
    float* out = (float*)d_out;

    const size_t half = ((size_t)out_size - 2) / 2;          // TOKENS*E*C
    const int C = (int)(half / ((size_t)TOKENS * E_));       // 40

    float* P = (float*)d_ws;
    size_t off = (size_t)KS * TOKENS * E_;
    int*   idx     = (int*)(P + off);   off += TOKENS;
    float* gate    = P + off;           off += TOKENS;
    float* probsum = P + off;           off += B_ * E_;

    float* out_aux = out + 2 * half;
    float* out_z   = out + 2 * half + 1;

    // K1 = pure-read GEMM, 1024 blocks (4/CU); K2 = softmax stats + NT
    // zero-fill of d_out; K3 = scatter. K1 block 0 zeroes probsum + losses.
    k_gemm<<<dim3(TOKENS / TM, KS), 256, 0, stream>>>(A, W, P, probsum, out_aux);
    k_softmax_z<<<TOKENS / 32, 256, 0, stream>>>(P, idx, gate, probsum, out_z,
                                                 out, C);
    k_posloss<<<B_ * E_, 64, 0, stream>>>(idx, gate, probsum, out, out_aux, C, half);
}